// Round 3
// baseline (32599.362 us; speedup 1.0000x reference)
//
#include <hip/hip_runtime.h>
#include <math.h>

#define DM   512
#define DS   128
#define TT   20
#define NL   4
#define NV   32000
#define NROW 2048

#define OFF_TI 0u   // ws: ti (2048*512 f32 = 4 MB)

// ---------------- dense, f32 numpy-faithful, one block per (b,s) row ----------------
// Replicates np-f32 semantics exactly:
//  * each matmul output element = single-accumulator ascending-k f32 FMA chain (sgemm)
//  * h@A.T + x@B.T computed as TWO chains, then ONE f32 add (np adds the arrays)
//  * h@C.T + x*D likewise: chain t3, elementwise t4, then t3 + t4
//  * LIF: v = v + (x - v)*0.5f (mul by 0.5 exact); spike v>=1; hard reset
//  * encode: f32 steps with correctly-rounded f32 exp
__global__ __launch_bounds__(256) void snn_f32_k(
    const int* __restrict__ ids, const float* __restrict__ emb,
    const float* __restrict__ A, const float* __restrict__ B,
    const float* __restrict__ C, const float* __restrict__ D,
    float* __restrict__ ti){
  __shared__ char xs[2][TT][DM];   // layer input / output spikes
  __shared__ char hs[DS];          // current h spikes
  int row = blockIdx.x;
  int tid = threadIdx.x;
  int id  = ids[row];

  // temporal encode, f32 step-faithful: sg = 1/(1+exp(-x)); k = floor(sg*19)
  for (int d = tid; d < DM; d += 256){
    float e    = emb[(size_t)id * DM + d];
    float ex32 = (float)exp(-(double)e);       // correctly-rounded f32 exp(-x)
    float sg   = 1.0f / (1.0f + ex32);         // f32 add, f32 div
    float p    = sg * 19.0f;                   // f32 mul
    int k = (int)floorf(p);
    if (k > TT-1) k = TT-1;
    #pragma unroll
    for (int t = 0; t < TT; t++) xs[0][t][d] = (char)(t == k);
  }

  int cur = 0;
  int cnt0 = 0, cnt1 = 0;
  for (int l = 0; l < NL; l++){
    const float* Al = A + l * DS * DS;
    const float* Bl = B + l * DS * DM;
    const float* Cl = C + l * DM * DS;
    const float* Dl = D + l * DM;
    float v1 = 0.0f, v2a = 0.0f, v2b = 0.0f;
    if (tid < DS) hs[tid] = 0;
    __syncthreads();

    for (int t = 0; t < TT; t++){
      // ---- LIF1: state_update = (h @ A.T) + (x_t @ B.T), state i = tid ----
      float su = 0.0f;
      if (tid < DS){
        float t1 = 0.0f;                       // h @ A.T chain (j ascending)
        const float* Ar = Al + tid * DS;
        for (int j = 0; j < DS; j++) if (hs[j]) t1 += Ar[j];
        float t2 = 0.0f;                       // x @ B.T chain (d ascending)
        const float* Br = Bl + (size_t)tid * DM;
        const char* xt = xs[cur][t];
        for (int d = 0; d < DM; d++) if (xt[d]) t2 += Br[d];
        su = t1 + t2;                          // np adds the two arrays once
      }
      __syncthreads();              // all reads of old hs complete
      if (tid < DS){
        v1 = v1 + (su - v1) * 0.5f; // v += (x - v)/tau, tau = 2 (exact *0.5)
        int s = (v1 >= 1.0f);
        hs[tid] = (char)s;
        if (s) v1 = 0.0f;           // hard reset
      }
      __syncthreads();              // new hs visible

      // ---- LIF2: output_update = (h_new @ C.T) + (x_t * D), d = tid, tid+256 ----
      {
        const char* xt = xs[cur][t];
        int d0 = tid, d1 = tid + 256;
        float t3a = 0.0f, t3b = 0.0f;          // h @ C.T chains (j ascending)
        const float* C0 = Cl + (size_t)d0 * DS;
        const float* C1 = Cl + (size_t)d1 * DS;
        for (int j = 0; j < DS; j++){
          if (hs[j]){ t3a += C0[j]; t3b += C1[j]; }
        }
        float t4a = xt[d0] ? Dl[d0] : 0.0f;    // x_t * D elementwise
        float t4b = xt[d1] ? Dl[d1] : 0.0f;
        float oa = t3a + t4a;                  // one add, np order
        float ob = t3b + t4b;
        v2a = v2a + (oa - v2a) * 0.5f;
        v2b = v2b + (ob - v2b) * 0.5f;
        int s0 = (v2a >= 1.0f), s1 = (v2b >= 1.0f);
        if (s0) v2a = 0.0f;
        if (s1) v2b = 0.0f;
        if (l < NL - 1){
          xs[cur ^ 1][t][d0] = (char)s0;
          xs[cur ^ 1][t][d1] = (char)s1;
        } else {
          cnt0 += s0; cnt1 += s1;
        }
      }
      __syncthreads();
    }
    cur ^= 1;
  }
  // time_integrated = mean over T: exact int count, one f32 divide (matches np)
  ti[(size_t)row * DM + tid]       = (float)cnt0 / 20.0f;
  ti[(size_t)row * DM + tid + 256] = (float)cnt1 / 20.0f;
}

// ---------------- final projection: (2048x512) @ (512x32000) + bp ----------------
// ascending-k single-accumulator fmaf chain per output element == np sgemm; bias added once at end
#define GP 132
__global__ __launch_bounds__(256) void bt_gemm_k(
    const float* __restrict__ ti, const float* __restrict__ Wp,
    const float* __restrict__ bp, float* __restrict__ out){
  __shared__ float sA[32][GP];
  __shared__ float sB[32][GP];
  int tid = threadIdx.x;
  int n0 = blockIdx.x * 128;
  int m0 = blockIdx.y * 128;
  float acc[8][8];
  #pragma unroll
  for (int i = 0; i < 8; i++)
    #pragma unroll
    for (int j = 0; j < 8; j++) acc[i][j] = 0.0f;

  int srow = tid >> 3;          // 0..31
  int scol = (tid & 7) * 4;     // 0,4,...,28
  int ty = tid >> 4, tx = tid & 15;

  for (int kc = 0; kc < 16; kc++){
    int k0 = kc * 32;
    __syncthreads();
    #pragma unroll
    for (int p = 0; p < 4; p++){
      int r = srow + p * 32;
      float4 va = *(const float4*)(ti + (size_t)(m0 + r) * 512 + k0 + scol);
      sA[scol+0][r] = va.x; sA[scol+1][r] = va.y; sA[scol+2][r] = va.z; sA[scol+3][r] = va.w;
      float4 vb = *(const float4*)(Wp + (size_t)(n0 + r) * 512 + k0 + scol);
      sB[scol+0][r] = vb.x; sB[scol+1][r] = vb.y; sB[scol+2][r] = vb.z; sB[scol+3][r] = vb.w;
    }
    __syncthreads();
    #pragma unroll 4
    for (int k = 0; k < 32; k++){
      float a[8], b[8];
      *(float4*)(a)     = *(const float4*)&sA[k][ty*8];
      *(float4*)(a + 4) = *(const float4*)&sA[k][ty*8 + 4];
      *(float4*)(b)     = *(const float4*)&sB[k][tx*8];
      *(float4*)(b + 4) = *(const float4*)&sB[k][tx*8 + 4];
      #pragma unroll
      for (int i = 0; i < 8; i++)
        #pragma unroll
        for (int j = 0; j < 8; j++) acc[i][j] = fmaf(a[i], b[j], acc[i][j]);
    }
  }
  float bpv[8];
  *(float4*)(bpv)     = *(const float4*)(bp + n0 + tx*8);
  *(float4*)(bpv + 4) = *(const float4*)(bp + n0 + tx*8 + 4);
  #pragma unroll
  for (int i = 0; i < 8; i++){
    float* orow = out + (size_t)(m0 + ty*8 + i) * NV + n0 + tx*8;
    float4 r0, r1;
    r0.x = acc[i][0] + bpv[0]; r0.y = acc[i][1] + bpv[1];
    r0.z = acc[i][2] + bpv[2]; r0.w = acc[i][3] + bpv[3];
    r1.x = acc[i][4] + bpv[4]; r1.y = acc[i][5] + bpv[5];
    r1.z = acc[i][6] + bpv[6]; r1.w = acc[i][7] + bpv[7];
    *(float4*)orow       = r0;
    *((float4*)orow + 1) = r1;
  }
}

extern "C" void kernel_launch(void* const* d_in, const int* in_sizes, int n_in,
                              void* d_out, int out_size, void* d_ws, size_t ws_size,
                              hipStream_t stream) {
  const int*   ids = (const int*)  d_in[0];
  const float* emb = (const float*)d_in[1];
  const float* A   = (const float*)d_in[2];
  const float* B   = (const float*)d_in[3];
  const float* C   = (const float*)d_in[4];
  const float* D   = (const float*)d_in[5];
  const float* Wp  = (const float*)d_in[6];
  const float* bp  = (const float*)d_in[7];
  float* out = (float*)d_out;
  float* ti  = (float*)((char*)d_ws + OFF_TI);

  snn_f32_k<<<dim3(NROW), dim3(256), 0, stream>>>(ids, emb, A, B, C, D, ti);
  bt_gemm_k <<<dim3(250, 16), dim3(256), 0, stream>>>(ti, Wp, bp, out);
}

// Round 4
// 1814.192 us; speedup vs baseline: 17.9691x; 17.9691x over previous
//
#include <hip/hip_runtime.h>
#include <math.h>

typedef unsigned int uint;
typedef unsigned long long ull;

#define DM   512
#define DS   128
#define TT   20
#define NL   4
#define NV   32000
#define NROW 2048

// ws layout
#define OFF_AT 0u          // 4*128*128 f32 = 262144      At[l][j][i] = A[l][i][j]
#define OFF_BT 262144u     // 4*512*128 f32 = 1048576     Bt[l][d][i] = B[l][i][d]
#define OFF_CT 1310720u    // 4*128*512 f32 = 1048576     Ct[l][j][d] = C[l][d][j]
#define OFF_X0 2359296u    // 2048*20*16 u32 = 2621440    spike masks ping (bit d&31 of word d>>5)
#define OFF_X1 4980736u    // 2621440                     spike masks pong
#define OFF_H  7602176u    // 2048*20*4 u32 = 655360      h masks
#define OFF_TI 8257536u    // 2048*512 f32 = 4194304      time-integrated

// ---------------- transpose weights (identical to r1) ----------------
__global__ __launch_bounds__(256) void bt_transpose_k(
    const float* __restrict__ A, const float* __restrict__ B, const float* __restrict__ C,
    float* __restrict__ At, float* __restrict__ Bt, float* __restrict__ Ct){
  int tid = blockIdx.x * 256 + threadIdx.x;
  int nth = gridDim.x * 256;
  for (int idx = tid; idx < 4*128*128; idx += nth){
    int l = idx >> 14, j = (idx >> 7) & 127, i = idx & 127;
    At[idx] = A[l*16384 + i*128 + j];
  }
  for (int idx = tid; idx < 4*512*128; idx += nth){
    int l = idx >> 16, d = (idx >> 7) & 511, i = idx & 127;
    Bt[idx] = B[l*65536 + i*512 + d];
  }
  for (int idx = tid; idx < 4*128*512; idx += nth){
    int l = idx >> 16, j = (idx >> 9) & 127, i = idx & 511;
    Ct[idx] = C[l*65536 + i*128 + j];
  }
}

// ---------------- temporal encode -> linear bitmasks ----------------
// X[r][t][w] bit b  <->  d = w*32 + b ; math byte-identical to passing round 3
__global__ __launch_bounds__(256) void enc_k(
    const int* __restrict__ ids, const float* __restrict__ emb, uint* __restrict__ X0){
  int tid = threadIdx.x;
  int h = tid & 31, rloc = tid >> 5;
  int r = blockIdx.x * 8 + rloc;
  int id = ids[r];
  uint half = (uint)((rloc & 1) * 32);
  int kk[16];
  #pragma unroll
  for (int w = 0; w < 16; w++){
    float e    = emb[(size_t)id * DM + w*32 + h];
    float ex32 = (float)exp(-(double)e);     // correctly-rounded f32 exp(-x)
    float sg   = 1.0f / (1.0f + ex32);
    float p    = sg * 19.0f;
    int k = (int)floorf(p);
    if (k > TT-1) k = TT-1;
    kk[w] = k;
  }
  uint* Xr = X0 + (size_t)r * (TT*16);
  for (int t = 0; t < TT; t++){
    #pragma unroll
    for (int w = 0; w < 16; w++){
      uint bw = (uint)(__ballot(kk[w] == t) >> half);
      if (h == 0) Xr[t*16 + w] = bw;
    }
  }
}

// ---------------- kernel A: T2 = X@B.T (all t) then LIF1 recurrence -> H ----------------
// block: 8 rows (4 waves; wave = 2 rows x 32 lanes). thread: row rloc, lanes h,
// owns states i = k*32+h (k=0..3), all 20 t. Chains: single f32 accumulator,
// ascending index -> bit-exact vs np (fmaf with 0/1 multiplier is skip/add).
__global__ __launch_bounds__(256, 1) void snn_a_k(
    int l, const uint* __restrict__ Xin, const float* __restrict__ At,
    const float* __restrict__ Bt, uint* __restrict__ H){
  __shared__ float At_l[128][129];
  __shared__ float Bt_l[128][129];
  __shared__ uint  X_l[8][TT][16];
  int tid = threadIdx.x;
  int h = tid & 31, rloc = tid >> 5;
  size_t rbase = (size_t)blockIdx.x * 8;

  { // stage At (layer) + X masks (8 rows)
    const float* Ag = At + l * 16384;
    #pragma unroll
    for (int p = 0; p < 16; p++){
      int i4 = tid + p*256; int j = i4 >> 5, c = (i4 & 31) * 4;
      float4 v = *(const float4*)(Ag + j*128 + c);
      At_l[j][c] = v.x; At_l[j][c+1] = v.y; At_l[j][c+2] = v.z; At_l[j][c+3] = v.w;
    }
    const uint4* Xg = (const uint4*)(Xin + rbase * (TT*16));
    uint4* Xs = (uint4*)&X_l[0][0][0];
    for (int p = tid; p < 8*TT*4; p += 256) Xs[p] = Xg[p];
  }

  float acc[TT][4];
  #pragma unroll
  for (int t = 0; t < TT; t++){ acc[t][0]=0.f; acc[t][1]=0.f; acc[t][2]=0.f; acc[t][3]=0.f; }

  // ---- B-phase: acc[t][k] = (x[t] @ B.T)[i=k*32+h], d ascending 0..511 ----
  for (int c = 0; c < 4; c++){
    __syncthreads();
    const float* Bg = Bt + l * 65536 + c * 128 * 128;
    #pragma unroll
    for (int p = 0; p < 16; p++){
      int i4 = tid + p*256; int d = i4 >> 5, cc = (i4 & 31) * 4;
      float4 v = *(const float4*)(Bg + d*128 + cc);
      Bt_l[d][cc] = v.x; Bt_l[d][cc+1] = v.y; Bt_l[d][cc+2] = v.z; Bt_l[d][cc+3] = v.w;
    }
    __syncthreads();
    for (int dw = 0; dw < 4; dw++){
      uint w20[TT];
      #pragma unroll
      for (int t = 0; t < TT; t++) w20[t] = X_l[rloc][t][c*4 + dw];
      for (int db = 0; db < 32; db++){
        int dr = dw*32 + db;
        float b0 = Bt_l[dr][h], b1 = Bt_l[dr][32+h], b2 = Bt_l[dr][64+h], b3 = Bt_l[dr][96+h];
        #pragma unroll
        for (int t = 0; t < TT; t++){
          float sf = (float)((w20[t] >> db) & 1u);
          acc[t][0] = fmaf(sf, b0, acc[t][0]);
          acc[t][1] = fmaf(sf, b1, acc[t][1]);
          acc[t][2] = fmaf(sf, b2, acc[t][2]);
          acc[t][3] = fmaf(sf, b3, acc[t][3]);
        }
      }
    }
  }

  // ---- LIF1 recurrence over t: su = (h@A.T chain) + acc ; ballot -> h masks ----
  float v1[4] = {0.f,0.f,0.f,0.f};
  uint m[4] = {0u,0u,0u,0u};
  uint half = (uint)((rloc & 1) * 32);
  size_t Hbase = (rbase + rloc) * TT;
  for (int t = 0; t < TT; t++){
    float t1[4] = {0.f,0.f,0.f,0.f};
    #pragma unroll
    for (int jw = 0; jw < 4; jw++){
      uint wj = m[jw];
      if (wj){
        for (int jb = 0; jb < 32; jb++){
          float sf = (float)((wj >> jb) & 1u);
          int j = jw*32 + jb;
          t1[0] = fmaf(sf, At_l[j][h],    t1[0]);
          t1[1] = fmaf(sf, At_l[j][32+h], t1[1]);
          t1[2] = fmaf(sf, At_l[j][64+h], t1[2]);
          t1[3] = fmaf(sf, At_l[j][96+h], t1[3]);
        }
      }
    }
    bool s[4];
    #pragma unroll
    for (int k = 0; k < 4; k++){
      float su = t1[k] + acc[t][k];          // np: (h@A.T) + (x@B.T), one add
      v1[k] = v1[k] + (su - v1[k]) * 0.5f;   // LIF, tau=2 (exact *0.5)
      s[k] = (v1[k] >= 1.0f);
      if (s[k]) v1[k] = 0.0f;                // hard reset
    }
    m[0] = (uint)(__ballot(s[0]) >> half);
    m[1] = (uint)(__ballot(s[1]) >> half);
    m[2] = (uint)(__ballot(s[2]) >> half);
    m[3] = (uint)(__ballot(s[3]) >> half);
    if (h == 0) *(uint4*)(H + (Hbase + t)*4) = make_uint4(m[0], m[1], m[2], m[3]);
  }
}

// ---------------- kernel B: T3 = H@C.T then LIF2 -> X' (or ti on last layer) ----------------
// 1024 blocks: rg = bid>>2 (8 rows), dg = bid&3 (128-d slice). thread owns
// d = dg*128 + k*32 + h (k=0..3), all 20 t.
__global__ __launch_bounds__(256, 1) void snn_b_k(
    int l, int last, const uint* __restrict__ Xin, const uint* __restrict__ H,
    const float* __restrict__ Ct, const float* __restrict__ Dfull,
    uint* __restrict__ Xout, float* __restrict__ ti){
  __shared__ float Ct_l[128][129];
  __shared__ uint  H_l[8][TT][4];
  __shared__ uint  X_l[8][TT][4];
  int tid = threadIdx.x;
  int h = tid & 31, rloc = tid >> 5;
  int rg = blockIdx.x >> 2, dg = blockIdx.x & 3;
  size_t rbase = (size_t)rg * 8;

  { // stage Ct slice [128 j][128 d], H masks, X quarter (for x*D term)
    const float* Cg = Ct + l * 65536 + dg * 128;
    #pragma unroll
    for (int p = 0; p < 16; p++){
      int i4 = tid + p*256; int j = i4 >> 5, c = (i4 & 31) * 4;
      float4 v = *(const float4*)(Cg + (size_t)j * 512 + c);
      Ct_l[j][c] = v.x; Ct_l[j][c+1] = v.y; Ct_l[j][c+2] = v.z; Ct_l[j][c+3] = v.w;
    }
    for (int p = tid; p < 8*TT; p += 256){
      int rr = p / TT, t = p % TT;
      *(uint4*)&H_l[rr][t][0] = *(const uint4*)(H + ((rbase + rr)*TT + t)*4);
      *(uint4*)&X_l[rr][t][0] = *(const uint4*)(Xin + ((rbase + rr)*TT + t)*16 + dg*4);
    }
  }
  __syncthreads();

  float acc[TT][4];
  #pragma unroll
  for (int t = 0; t < TT; t++){ acc[t][0]=0.f; acc[t][1]=0.f; acc[t][2]=0.f; acc[t][3]=0.f; }

  // ---- acc[t][k] = (h[t] @ C.T)[d], j ascending 0..127, single chain ----
  for (int jw = 0; jw < 4; jw++){
    uint w20[TT];
    #pragma unroll
    for (int t = 0; t < TT; t++) w20[t] = H_l[rloc][t][jw];
    for (int jb = 0; jb < 32; jb++){
      int j = jw*32 + jb;
      float c0 = Ct_l[j][h], c1 = Ct_l[j][32+h], c2 = Ct_l[j][64+h], c3 = Ct_l[j][96+h];
      #pragma unroll
      for (int t = 0; t < TT; t++){
        float sf = (float)((w20[t] >> jb) & 1u);
        acc[t][0] = fmaf(sf, c0, acc[t][0]);
        acc[t][1] = fmaf(sf, c1, acc[t][1]);
        acc[t][2] = fmaf(sf, c2, acc[t][2]);
        acc[t][3] = fmaf(sf, c3, acc[t][3]);
      }
    }
  }

  // ---- LIF2 over t ----
  size_t r = rbase + rloc;
  float dv[4];
  #pragma unroll
  for (int k = 0; k < 4; k++) dv[k] = Dfull[l*DM + dg*128 + k*32 + h];
  float v2[4] = {0.f,0.f,0.f,0.f};
  int cnt[4] = {0,0,0,0};
  uint half = (uint)((rloc & 1) * 32);
  for (int t = 0; t < TT; t++){
    bool s[4];
    #pragma unroll
    for (int k = 0; k < 4; k++){
      float t4 = ((X_l[rloc][t][k] >> h) & 1u) ? dv[k] : 0.0f;  // x_t * D (exact)
      float ou = acc[t][k] + t4;              // np: (h@C.T) + x*D, one add
      v2[k] = v2[k] + (ou - v2[k]) * 0.5f;
      s[k] = (v2[k] >= 1.0f);
      if (s[k]) v2[k] = 0.0f;
    }
    if (!last){
      #pragma unroll
      for (int k = 0; k < 4; k++){
        uint w = (uint)(__ballot(s[k]) >> half);
        if (h == 0) Xout[((size_t)r*TT + t)*16 + dg*4 + k] = w;
      }
    } else {
      #pragma unroll
      for (int k = 0; k < 4; k++) cnt[k] += s[k] ? 1 : 0;
    }
  }
  if (last){
    #pragma unroll
    for (int k = 0; k < 4; k++)
      ti[r*DM + dg*128 + k*32 + h] = (float)cnt[k] / 20.0f;
  }
}

// ---------------- final projection (unchanged from passing round 3) ----------------
#define GP 132
__global__ __launch_bounds__(256) void bt_gemm_k(
    const float* __restrict__ ti, const float* __restrict__ Wp,
    const float* __restrict__ bp, float* __restrict__ out){
  __shared__ float sA[32][GP];
  __shared__ float sB[32][GP];
  int tid = threadIdx.x;
  int n0 = blockIdx.x * 128;
  int m0 = blockIdx.y * 128;
  float acc[8][8];
  #pragma unroll
  for (int i = 0; i < 8; i++)
    #pragma unroll
    for (int j = 0; j < 8; j++) acc[i][j] = 0.0f;

  int srow = tid >> 3;
  int scol = (tid & 7) * 4;
  int ty = tid >> 4, tx = tid & 15;

  for (int kc = 0; kc < 16; kc++){
    int k0 = kc * 32;
    __syncthreads();
    #pragma unroll
    for (int p = 0; p < 4; p++){
      int r = srow + p * 32;
      float4 va = *(const float4*)(ti + (size_t)(m0 + r) * 512 + k0 + scol);
      sA[scol+0][r] = va.x; sA[scol+1][r] = va.y; sA[scol+2][r] = va.z; sA[scol+3][r] = va.w;
      float4 vb = *(const float4*)(Wp + (size_t)(n0 + r) * 512 + k0 + scol);
      sB[scol+0][r] = vb.x; sB[scol+1][r] = vb.y; sB[scol+2][r] = vb.z; sB[scol+3][r] = vb.w;
    }
    __syncthreads();
    #pragma unroll 4
    for (int k = 0; k < 32; k++){
      float a[8], b[8];
      *(float4*)(a)     = *(const float4*)&sA[k][ty*8];
      *(float4*)(a + 4) = *(const float4*)&sA[k][ty*8 + 4];
      *(float4*)(b)     = *(const float4*)&sB[k][tx*8];
      *(float4*)(b + 4) = *(const float4*)&sB[k][tx*8 + 4];
      #pragma unroll
      for (int i = 0; i < 8; i++)
        #pragma unroll
        for (int j = 0; j < 8; j++) acc[i][j] = fmaf(a[i], b[j], acc[i][j]);
    }
  }
  float bpv[8];
  *(float4*)(bpv)     = *(const float4*)(bp + n0 + tx*8);
  *(float4*)(bpv + 4) = *(const float4*)(bp + n0 + tx*8 + 4);
  #pragma unroll
  for (int i = 0; i < 8; i++){
    float* orow = out + (size_t)(m0 + ty*8 + i) * NV + n0 + tx*8;
    float4 r0, r1;
    r0.x = acc[i][0] + bpv[0]; r0.y = acc[i][1] + bpv[1];
    r0.z = acc[i][2] + bpv[2]; r0.w = acc[i][3] + bpv[3];
    r1.x = acc[i][4] + bpv[4]; r1.y = acc[i][5] + bpv[5];
    r1.z = acc[i][6] + bpv[6]; r1.w = acc[i][7] + bpv[7];
    *(float4*)orow       = r0;
    *((float4*)orow + 1) = r1;
  }
}

extern "C" void kernel_launch(void* const* d_in, const int* in_sizes, int n_in,
                              void* d_out, int out_size, void* d_ws, size_t ws_size,
                              hipStream_t stream) {
  const int*   ids = (const int*)  d_in[0];
  const float* emb = (const float*)d_in[1];
  const float* A   = (const float*)d_in[2];
  const float* B   = (const float*)d_in[3];
  const float* C   = (const float*)d_in[4];
  const float* D   = (const float*)d_in[5];
  const float* Wp  = (const float*)d_in[6];
  const float* bp  = (const float*)d_in[7];
  float* out = (float*)d_out;
  char* ws = (char*)d_ws;
  float* At = (float*)(ws + OFF_AT);
  float* Bt = (float*)(ws + OFF_BT);
  float* Ct = (float*)(ws + OFF_CT);
  uint*  X0 = (uint*) (ws + OFF_X0);
  uint*  X1 = (uint*) (ws + OFF_X1);
  uint*  H  = (uint*) (ws + OFF_H);
  float* ti = (float*)(ws + OFF_TI);

  bt_transpose_k<<<dim3(512), dim3(256), 0, stream>>>(A, B, C, At, Bt, Ct);
  enc_k         <<<dim3(256), dim3(256), 0, stream>>>(ids, emb, X0);
  for (int l = 0; l < NL; l++){
    uint* Xin  = (l & 1) ? X1 : X0;
    uint* Xout = (l & 1) ? X0 : X1;
    snn_a_k<<<dim3(256),  dim3(256), 0, stream>>>(l, Xin, At, Bt, H);
    snn_b_k<<<dim3(1024), dim3(256), 0, stream>>>(l, (l == NL-1) ? 1 : 0, Xin, H, Ct, D, Xout, ti);
  }
  bt_gemm_k<<<dim3(250, 16), dim3(256), 0, stream>>>(ti, Wp, bp, out);
}

// Round 5
// 1231.743 us; speedup vs baseline: 26.4661x; 1.4729x over previous
//
#include <hip/hip_runtime.h>
#include <math.h>

typedef unsigned int uint;
typedef unsigned long long ull;
typedef unsigned short ushort;

#define DM   512
#define DS   128
#define TT   20
#define NL   4
#define NV   32000
#define NROW 2048

// ws layout (~10.4 MB)
#define OFF_AT  0u          // 4*128*128 f32    At[l][j][i] = A[l][i][j]
#define OFF_BT  262144u     // 4*512*128 f32    Bt[l][d][i] = B[l][i][d]
#define OFF_CT  1310720u    // 4*128*512 f32    Ct[l][j][d] = C[l][d][j]
#define OFF_X0  2359296u    // 2048*20*16 u32   spike masks ping (bit d&31 of word d>>5)
#define OFF_X1  4980736u    // 2621440          spike masks pong
#define OFF_H   7602176u    // 2048*20*4 u32    h masks
#define OFF_TIB 8257536u    // 2048*512 bf16    time-integrated (bf16 for MFMA GEMM)

typedef float f32x4 __attribute__((ext_vector_type(4)));
typedef __bf16 bf16x8 __attribute__((ext_vector_type(8)));
typedef ushort us8 __attribute__((ext_vector_type(8)));

__device__ __forceinline__ ushort f2bf(float f){   // RNE f32->bf16 (finite inputs)
  uint x = __float_as_uint(f);
  uint r = x + 0x7fffu + ((x >> 16) & 1u);
  return (ushort)(r >> 16);
}

// ---------------- transpose weights ----------------
__global__ __launch_bounds__(256) void bt_transpose_k(
    const float* __restrict__ A, const float* __restrict__ B, const float* __restrict__ C,
    float* __restrict__ At, float* __restrict__ Bt, float* __restrict__ Ct){
  int tid = blockIdx.x * 256 + threadIdx.x;
  int nth = gridDim.x * 256;
  for (int idx = tid; idx < 4*128*128; idx += nth){
    int l = idx >> 14, j = (idx >> 7) & 127, i = idx & 127;
    At[idx] = A[l*16384 + i*128 + j];
  }
  for (int idx = tid; idx < 4*512*128; idx += nth){
    int l = idx >> 16, d = (idx >> 7) & 511, i = idx & 127;
    Bt[idx] = B[l*65536 + i*512 + d];
  }
  for (int idx = tid; idx < 4*128*512; idx += nth){
    int l = idx >> 16, j = (idx >> 9) & 127, i = idx & 511;
    Ct[idx] = C[l*65536 + i*128 + j];
  }
}

// ---------------- temporal encode -> bitmasks (verified round 4) ----------------
__global__ __launch_bounds__(256) void enc_k(
    const int* __restrict__ ids, const float* __restrict__ emb, uint* __restrict__ X0){
  int tid = threadIdx.x;
  int h = tid & 31, rloc = tid >> 5;
  int r = blockIdx.x * 8 + rloc;
  int id = ids[r];
  uint half = (uint)((rloc & 1) * 32);
  int kk[16];
  #pragma unroll
  for (int w = 0; w < 16; w++){
    float e    = emb[(size_t)id * DM + w*32 + h];
    float ex32 = (float)exp(-(double)e);     // correctly-rounded f32 exp(-x)
    float sg   = 1.0f / (1.0f + ex32);
    float p    = sg * 19.0f;
    int k = (int)floorf(p);
    if (k > TT-1) k = TT-1;
    kk[w] = k;
  }
  uint* Xr = X0 + (size_t)r * (TT*16);
  for (int t = 0; t < TT; t++){
    #pragma unroll
    for (int w = 0; w < 16; w++){
      uint bw = (uint)(__ballot(kk[w] == t) >> half);
      if (h == 0) Xr[t*16 + w] = bw;
    }
  }
}

// ---------------- kernel A: X@B.T (all t) then LIF1 recurrence -> H ----------------
// 8 rows/block (row = 32 lanes, 4 states/lane). Layer 0: one-hot sparse B via
// chunked LDS; layers>=1: dense from global (L2) with 20-t register reuse.
// All chains: single f32 accumulator, ascending index (bit-exact vs np).
__global__ __launch_bounds__(256, 1) void snn_a_k(
    int l, const uint* __restrict__ Xin, const float* __restrict__ At,
    const float* __restrict__ Bt, uint* __restrict__ H){
  __shared__ float WB[128][130];     // Bt chunks (l=0 B-phase), then At (recurrence)
  __shared__ uint  X_l[8][TT][16];
  int tid = threadIdx.x;
  int h = tid & 31, rloc = tid >> 5;
  size_t rbase = (size_t)blockIdx.x * 8;

  { // stage X masks (8 rows)
    const uint4* Xg = (const uint4*)(Xin + rbase * (TT*16));
    uint4* Xs = (uint4*)&X_l[0][0][0];
    for (int p = tid; p < 8*TT*4; p += 256) Xs[p] = Xg[p];
  }
  __syncthreads();

  float acc[TT][4];
  #pragma unroll
  for (int t = 0; t < TT; t++){ acc[t][0]=0.f; acc[t][1]=0.f; acc[t][2]=0.f; acc[t][3]=0.f; }

  if (l == 0){
    // one-hot sparse: each d fires at exactly one t; add == fmaf(1,b,acc) exactly,
    // skipped d == fmaf(0,b,acc) identity. Ascending d: chunks, words, bits.
    for (int c = 0; c < 4; c++){
      __syncthreads();
      const float* Bg = Bt + c * 128 * 128;
      #pragma unroll
      for (int p = 0; p < 16; p++){
        int i4 = tid + p*256; int d = i4 >> 5, cc = (i4 & 31) * 4;
        float4 v = *(const float4*)(Bg + d*128 + cc);
        WB[d][cc] = v.x; WB[d][cc+1] = v.y; WB[d][cc+2] = v.z; WB[d][cc+3] = v.w;
      }
      __syncthreads();
      for (int t = 0; t < TT; t++){
        #pragma unroll
        for (int w = 0; w < 4; w++){
          uint m = X_l[rloc][t][c*4 + w];
          while (m){
            int b = __builtin_ctz(m); m &= m - 1;
            int dl = w*32 + b;
            acc[t][0] += WB[dl][h];    acc[t][1] += WB[dl][32+h];
            acc[t][2] += WB[dl][64+h]; acc[t][3] += WB[dl][96+h];
          }
        }
      }
    }
  } else {
    const float* Bg = Bt + l * 65536;
    for (int dw = 0; dw < 16; dw++){
      uint w20[TT];
      #pragma unroll
      for (int t = 0; t < TT; t++) w20[t] = X_l[rloc][t][dw];
      #pragma unroll 2
      for (int db = 0; db < 32; db++){
        const float* bp_ = Bg + (dw*32 + db) * 128;
        float b0 = bp_[h], b1 = bp_[32+h], b2 = bp_[64+h], b3 = bp_[96+h];
        #pragma unroll
        for (int t = 0; t < TT; t++){
          float sf = (float)((w20[t] >> db) & 1u);
          acc[t][0] = fmaf(sf, b0, acc[t][0]);
          acc[t][1] = fmaf(sf, b1, acc[t][1]);
          acc[t][2] = fmaf(sf, b2, acc[t][2]);
          acc[t][3] = fmaf(sf, b3, acc[t][3]);
        }
      }
    }
  }

  // stage At into WB, then LIF1 recurrence (identical math to round 4)
  __syncthreads();
  {
    const float* Ag = At + l * 16384;
    #pragma unroll
    for (int p = 0; p < 16; p++){
      int i4 = tid + p*256; int j = i4 >> 5, c = (i4 & 31) * 4;
      float4 v = *(const float4*)(Ag + j*128 + c);
      WB[j][c] = v.x; WB[j][c+1] = v.y; WB[j][c+2] = v.z; WB[j][c+3] = v.w;
    }
  }
  __syncthreads();

  float v1[4] = {0.f,0.f,0.f,0.f};
  uint m[4] = {0u,0u,0u,0u};
  uint half = (uint)((rloc & 1) * 32);
  size_t Hbase = (rbase + rloc) * TT;
  for (int t = 0; t < TT; t++){
    float t1[4] = {0.f,0.f,0.f,0.f};
    #pragma unroll
    for (int jw = 0; jw < 4; jw++){
      uint wj = m[jw];
      if (wj){
        for (int jb = 0; jb < 32; jb++){
          float sf = (float)((wj >> jb) & 1u);
          int j = jw*32 + jb;
          t1[0] = fmaf(sf, WB[j][h],    t1[0]);
          t1[1] = fmaf(sf, WB[j][32+h], t1[1]);
          t1[2] = fmaf(sf, WB[j][64+h], t1[2]);
          t1[3] = fmaf(sf, WB[j][96+h], t1[3]);
        }
      }
    }
    bool s[4];
    #pragma unroll
    for (int k = 0; k < 4; k++){
      float su = t1[k] + acc[t][k];          // np: (h@A.T) + (x@B.T), one add
      v1[k] = v1[k] + (su - v1[k]) * 0.5f;   // LIF, tau=2
      s[k] = (v1[k] >= 1.0f);
      if (s[k]) v1[k] = 0.0f;                // hard reset
    }
    m[0] = (uint)(__ballot(s[0]) >> half);
    m[1] = (uint)(__ballot(s[1]) >> half);
    m[2] = (uint)(__ballot(s[2]) >> half);
    m[3] = (uint)(__ballot(s[3]) >> half);
    if (h == 0) *(uint4*)(H + (Hbase + t)*4) = make_uint4(m[0], m[1], m[2], m[3]);
  }
}

// ---------------- kernel B: H@C.T then LIF2 -> X' (bf16 ti on last layer) ----------------
// 64-lane waves: block = 2 rows x 2 half-d waves (1024 blocks, 4 blk/CU).
// Wave covers 256 d; lane owns d = dgw*256 + k*64 + lane. C from global (L2)
// with 20-t register reuse. No LDS.
__global__ __launch_bounds__(256) void snn_b_k(
    int l, int last, const uint* __restrict__ Xin, const uint* __restrict__ Hg,
    const float* __restrict__ Ct, const float* __restrict__ Dfull,
    uint* __restrict__ Xout, ushort* __restrict__ tib){
  int tid = threadIdx.x;
  int lane = tid & 63, wv = tid >> 6;
  int rloc = wv >> 1, dgw = wv & 1;
  size_t r = (size_t)blockIdx.x * 2 + rloc;

  float acc[TT][4];
  #pragma unroll
  for (int t = 0; t < TT; t++){ acc[t][0]=0.f; acc[t][1]=0.f; acc[t][2]=0.f; acc[t][3]=0.f; }

  const float* Cl = Ct + l*65536 + dgw*256 + lane;
  const uint*  Hr = Hg + r * (TT*4);
  for (int jw = 0; jw < 4; jw++){
    uint Hw[TT];
    #pragma unroll
    for (int t = 0; t < TT; t++) Hw[t] = Hr[t*4 + jw];
    #pragma unroll 2
    for (int jb = 0; jb < 32; jb++){
      const float* cp = Cl + (size_t)(jw*32 + jb) * 512;
      float c0 = cp[0], c1 = cp[64], c2 = cp[128], c3 = cp[192];
      #pragma unroll
      for (int t = 0; t < TT; t++){
        float sf = (float)((Hw[t] >> jb) & 1u);
        acc[t][0] = fmaf(sf, c0, acc[t][0]);
        acc[t][1] = fmaf(sf, c1, acc[t][1]);
        acc[t][2] = fmaf(sf, c2, acc[t][2]);
        acc[t][3] = fmaf(sf, c3, acc[t][3]);
      }
    }
  }

  // LIF2 over t
  float dv[4];
  #pragma unroll
  for (int k = 0; k < 4; k++) dv[k] = Dfull[l*DM + dgw*256 + k*64 + lane];
  float v2[4] = {0.f,0.f,0.f,0.f};
  int cnt[4] = {0,0,0,0};
  const uint* Xr = Xin + r * (TT*16) + dgw*8 + (lane >> 5);
  for (int t = 0; t < TT; t++){
    bool s[4];
    #pragma unroll
    for (int k = 0; k < 4; k++){
      uint xw = Xr[t*16 + k*2];
      float t4 = ((xw >> (lane & 31)) & 1u) ? dv[k] : 0.0f;  // x_t * D
      float ou = acc[t][k] + t4;              // np: (h@C.T) + x*D, one add
      v2[k] = v2[k] + (ou - v2[k]) * 0.5f;
      s[k] = (v2[k] >= 1.0f);
      if (s[k]) v2[k] = 0.0f;
    }
    if (!last){
      #pragma unroll
      for (int k = 0; k < 4; k++){
        ull bm = __ballot(s[k]);
        if (lane == 0){
          Xout[(r*TT + t)*16 + dgw*8 + k*2]     = (uint)bm;
          Xout[(r*TT + t)*16 + dgw*8 + k*2 + 1] = (uint)(bm >> 32);
        }
      }
    } else {
      #pragma unroll
      for (int k = 0; k < 4; k++) cnt[k] += s[k] ? 1 : 0;
    }
  }
  if (last){
    #pragma unroll
    for (int k = 0; k < 4; k++)
      tib[r*DM + dgw*256 + k*64 + lane] = f2bf((float)cnt[k] / 20.0f);
  }
}

// ---------------- final projection: bf16 MFMA, (2048x512)@(512x32000)^T + bp ----------------
// BM=BN=128, BK=64, 4 waves (2x2), each wave 64x64 via 4x4 of 16x16x32 MFMA.
// A tile (tib) staged via global_load_lds w/ source-side XOR swizzle; B tile (Wp)
// reg-staged f32->bf16 with swizzled ds_write. Swizzle: elem col ^= (row&7)*8.
__global__ __launch_bounds__(256) void gemm_mfma_k(
    const ushort* __restrict__ tib, const float* __restrict__ Wp,
    const float* __restrict__ bp, float* __restrict__ out){
  __shared__ ushort lA[128*64];
  __shared__ ushort lB[128*64];
  int tid = threadIdx.x;
  int lane = tid & 63, wv = tid >> 6;
  int wm = wv >> 1, wn = wv & 1;
  int n0 = blockIdx.x * 128;
  int m0 = blockIdx.y * 128;

  f32x4 acc[4][4];
  #pragma unroll
  for (int i = 0; i < 4; i++)
    #pragma unroll
    for (int j = 0; j < 4; j++) acc[i][j] = (f32x4){0.f,0.f,0.f,0.f};

  for (int k0 = 0; k0 < 512; k0 += 64){
    __syncthreads();
    #pragma unroll
    for (int i = 0; i < 4; i++){     // A: global_load_lds 16B, pre-swizzled source
      int slot = tid + i*256; int row = slot >> 3; int cb8 = (slot & 7) * 8;
      int sc = cb8 ^ ((row & 7) * 8);
      const ushort* gp = tib + (size_t)(m0 + row) * 512 + k0 + sc;
      __builtin_amdgcn_global_load_lds((const __attribute__((address_space(1))) void*)gp,
          (__attribute__((address_space(3))) void*)&lA[slot*8], 16, 0, 0);
    }
    #pragma unroll
    for (int i = 0; i < 4; i++){     // B: reg-stage f32 -> bf16, swizzled dest
      int slot = tid + i*256; int row = slot >> 3; int cb8 = (slot & 7) * 8;
      int sc = cb8 ^ ((row & 7) * 8);
      const float* gp = Wp + (size_t)(n0 + row) * 512 + k0 + sc;
      float4 u = *(const float4*)gp;
      float4 v = *(const float4*)(gp + 4);
      us8 pk;
      pk[0]=f2bf(u.x); pk[1]=f2bf(u.y); pk[2]=f2bf(u.z); pk[3]=f2bf(u.w);
      pk[4]=f2bf(v.x); pk[5]=f2bf(v.y); pk[6]=f2bf(v.z); pk[7]=f2bf(v.w);
      *(us8*)&lB[slot*8] = pk;
    }
    __syncthreads();
    #pragma unroll
    for (int kk = 0; kk < 2; kk++){
      bf16x8 af[4], bf_[4];
      int c = kk*32 + (lane >> 4) * 8;
      #pragma unroll
      for (int mi = 0; mi < 4; mi++){
        int row = wm*64 + mi*16 + (lane & 15);
        af[mi] = *(const bf16x8*)&lA[row*64 + (c ^ ((row & 7) * 8))];
      }
      #pragma unroll
      for (int ni = 0; ni < 4; ni++){
        int row = wn*64 + ni*16 + (lane & 15);
        bf_[ni] = *(const bf16x8*)&lB[row*64 + (c ^ ((row & 7) * 8))];
      }
      #pragma unroll
      for (int mi = 0; mi < 4; mi++)
        #pragma unroll
        for (int ni = 0; ni < 4; ni++)
          acc[mi][ni] = __builtin_amdgcn_mfma_f32_16x16x32_bf16(af[mi], bf_[ni], acc[mi][ni], 0, 0, 0);
    }
  }

  // epilogue: D[(lane>>4)*4 + rr][lane&15] per 16x16 tile; + bias
  #pragma unroll
  for (int ni = 0; ni < 4; ni++){
    int col = n0 + wn*64 + ni*16 + (lane & 15);
    float bb = bp[col];
    #pragma unroll
    for (int mi = 0; mi < 4; mi++){
      int rbase_ = m0 + wm*64 + mi*16 + (lane >> 4) * 4;
      #pragma unroll
      for (int rr = 0; rr < 4; rr++)
        out[(size_t)(rbase_ + rr) * NV + col] = acc[mi][ni][rr] + bb;
    }
  }
}

extern "C" void kernel_launch(void* const* d_in, const int* in_sizes, int n_in,
                              void* d_out, int out_size, void* d_ws, size_t ws_size,
                              hipStream_t stream) {
  const int*   ids = (const int*)  d_in[0];
  const float* emb = (const float*)d_in[1];
  const float* A   = (const float*)d_in[2];
  const float* B   = (const float*)d_in[3];
  const float* C   = (const float*)d_in[4];
  const float* D   = (const float*)d_in[5];
  const float* Wp  = (const float*)d_in[6];
  const float* bp  = (const float*)d_in[7];
  float* out = (float*)d_out;
  char* ws = (char*)d_ws;
  float*  At  = (float*) (ws + OFF_AT);
  float*  Bt  = (float*) (ws + OFF_BT);
  float*  Ct  = (float*) (ws + OFF_CT);
  uint*   X0  = (uint*)  (ws + OFF_X0);
  uint*   X1  = (uint*)  (ws + OFF_X1);
  uint*   H   = (uint*)  (ws + OFF_H);
  ushort* tib = (ushort*)(ws + OFF_TIB);

  bt_transpose_k<<<dim3(512), dim3(256), 0, stream>>>(A, B, C, At, Bt, Ct);
  enc_k         <<<dim3(256), dim3(256), 0, stream>>>(ids, emb, X0);
  for (int l = 0; l < NL; l++){
    uint* Xin  = (l & 1) ? X1 : X0;
    uint* Xout = (l & 1) ? X0 : X1;
    snn_a_k<<<dim3(256),  dim3(256), 0, stream>>>(l, Xin, At, Bt, H);
    snn_b_k<<<dim3(1024), dim3(256), 0, stream>>>(l, (l == NL-1) ? 1 : 0, Xin, H, Ct, D, Xout, tib);
  }
  gemm_mfma_k<<<dim3(250, 16), dim3(256), 0, stream>>>(tib, Wp, bp, out);
}